// Round 1
// baseline (171.804 us; speedup 1.0000x reference)
//
#include <hip/hip_runtime.h>
#include <math.h>

// PyramidROIAlign: B=2, N=1000, C=256, POOL=7x7
// p3: [2,128,128,256], p4: [2,64,64,256], p5: [2,32,32,256], all fp32 NHWC.
// Output: [2,1000,7,7,256] fp32.
//
// Mapping: one 64-lane wave per (box, pool_y, pool_x); lane handles 4
// channels as float4. Scalar math is wave-uniform (box/level/weights),
// loads/stores are 1 KiB contiguous per wave -> fully coalesced.

#define NBOX   2000   // B*N
#define N_PER_B 1000
#define CCH    256
#define PH     7
#define PW     7
#define NPOS   (PH * PW)

__global__ __launch_bounds__(256) void pyramid_roi_align_kernel(
    const float* __restrict__ boxes,   // [2000,4] y1,x1,y2,x2
    const float* __restrict__ p3,      // [2,128,128,256]
    const float* __restrict__ p4,      // [2,64,64,256]
    const float* __restrict__ p5,      // [2,32,32,256]
    float* __restrict__ out)           // [2000,49,256]
{
    const int tid  = blockIdx.x * blockDim.x + threadIdx.x;
    const int lane = threadIdx.x & 63;
    const int gpos = tid >> 6;                 // (box * 49 + pos)
    if (gpos >= NBOX * NPOS) return;

    const int box = gpos / NPOS;
    const int pos = gpos - box * NPOS;
    const int iy  = pos / PW;
    const int ix  = pos - iy * PW;

    // Box coords (wave-uniform; cached broadcast)
    const float y1 = boxes[box * 4 + 0];
    const float x1 = boxes[box * 4 + 1];
    const float y2 = boxes[box * 4 + 2];
    const float x2 = boxes[box * 4 + 3];
    const float h  = y2 - y1;
    const float w  = x2 - x1;

    // roi_level = clip(ceil(5 + log(h*w)/log(2)), 3, 5)  -- match ref op order
    const float lvl = ceilf(5.0f + logf(h * w) / 0.69314718055994530942f);
    const float lvlc = fminf(fmaxf(lvl, 3.0f), 5.0f);
    const int level = (int)lvlc;

    const float* feat;
    int H;
    if (level <= 3)      { feat = p3; H = 128; }
    else if (level == 4) { feat = p4; H = 64;  }
    else                 { feat = p5; H = 32;  }
    const int W = H;

    const int b = (box >= N_PER_B) ? 1 : 0;
    feat += (size_t)b * H * W * CCH;

    const float Hm1 = (float)(H - 1);
    const float Wm1 = (float)(W - 1);

    // ys = y1*(H-1) + iy * ((y2-y1)*(H-1)/(ph-1))   (match reference exactly)
    const float ys = y1 * Hm1 + (float)iy * (h * Hm1 / 6.0f);
    const float xs = x1 * Wm1 + (float)ix * (w * Wm1 / 6.0f);

    const bool vy = (ys >= 0.0f) && (ys <= Hm1);
    const bool vx = (xs >= 0.0f) && (xs <= Wm1);
    const bool valid = vy && vx;

    const float y0f = floorf(ys);
    const float x0f = floorf(xs);
    const float wy  = ys - y0f;
    const float wx  = xs - x0f;

    const int y0i = (int)fminf(fmaxf(y0f,        0.0f), Hm1);
    const int y1i = (int)fminf(fmaxf(y0f + 1.0f, 0.0f), Hm1);
    const int x0i = (int)fminf(fmaxf(x0f,        0.0f), Wm1);
    const int x1i = (int)fminf(fmaxf(x0f + 1.0f, 0.0f), Wm1);

    const int c = lane * 4;
    const float4* r00 = (const float4*)(feat + ((size_t)(y0i * W + x0i)) * CCH + c);
    const float4* r01 = (const float4*)(feat + ((size_t)(y0i * W + x1i)) * CCH + c);
    const float4* r10 = (const float4*)(feat + ((size_t)(y1i * W + x0i)) * CCH + c);
    const float4* r11 = (const float4*)(feat + ((size_t)(y1i * W + x1i)) * CCH + c);

    const float4 v00 = *r00;
    const float4 v01 = *r01;
    const float4 v10 = *r10;
    const float4 v11 = *r11;

    const float omwx = 1.0f - wx;
    const float omwy = 1.0f - wy;

    float4 res;
    {
        const float t0 = v00.x * omwx + v01.x * wx;
        const float b0 = v10.x * omwx + v11.x * wx;
        res.x = t0 * omwy + b0 * wy;
        const float t1 = v00.y * omwx + v01.y * wx;
        const float b1 = v10.y * omwx + v11.y * wx;
        res.y = t1 * omwy + b1 * wy;
        const float t2 = v00.z * omwx + v01.z * wx;
        const float b2 = v10.z * omwx + v11.z * wx;
        res.z = t2 * omwy + b2 * wy;
        const float t3 = v00.w * omwx + v01.w * wx;
        const float b3 = v10.w * omwx + v11.w * wx;
        res.w = t3 * omwy + b3 * wy;
    }

    if (!valid) { res.x = 0.0f; res.y = 0.0f; res.z = 0.0f; res.w = 0.0f; }

    float4* dst = (float4*)(out + (size_t)gpos * CCH + c);
    *dst = res;
}

extern "C" void kernel_launch(void* const* d_in, const int* in_sizes, int n_in,
                              void* d_out, int out_size, void* d_ws, size_t ws_size,
                              hipStream_t stream) {
    const float* boxes = (const float*)d_in[0];
    // d_in[1] = positive_indices (unused by reference)
    const float* p3 = (const float*)d_in[2];
    const float* p4 = (const float*)d_in[3];
    const float* p5 = (const float*)d_in[4];
    // d_in[5] = config (unused)
    float* out = (float*)d_out;

    const int total_threads = NBOX * NPOS * 64;   // 6,272,000
    const int block = 256;
    const int grid = (total_threads + block - 1) / block;  // 24,500

    hipLaunchKernelGGL(pyramid_roi_align_kernel, dim3(grid), dim3(block), 0, stream,
                       boxes, p3, p4, p5, out);
}

// Round 2
// 168.888 us; speedup vs baseline: 1.0173x; 1.0173x over previous
//
#include <hip/hip_runtime.h>
#include <math.h>

// PyramidROIAlign: B=2, N=1000, C=256, POOL=7x7
// p3: [2,128,128,256], p4: [2,64,64,256], p5: [2,32,32,256], all fp32 NHWC.
// Output: [2,1000,7,7,256] fp32.
//
// R2 mapping: one block (448 thr = 7 waves) per box; wave = pool row iy;
// lane covers 4 channels (float4). Scalar setup (box math, log-level,
// y-coords) runs once per 7 outputs instead of once per output --
// R1 was VALU-issue-bound (VALUBusy 48%, hbm only 51% peak) because all
// 64 lanes repeated the ~45-instr setup per 1KB tile.
// Block==box also keeps each box's ~64KB corner footprint on one XCD L2.

#define N_PER_B 1000
#define NBOX    2000   // B*N
#define CCH     256
#define PH      7
#define PW      7

__global__ __launch_bounds__(448, 4) void pyramid_roi_align_kernel(
    const float* __restrict__ boxes,   // [2000,4] y1,x1,y2,x2
    const float* __restrict__ p3,      // [2,128,128,256]
    const float* __restrict__ p4,      // [2,64,64,256]
    const float* __restrict__ p5,      // [2,32,32,256]
    float* __restrict__ out)           // [2000,49,256]
{
    const int box  = blockIdx.x;
    const int iy   = threadIdx.x >> 6;   // wave id = pool row, 0..6
    const int lane = threadIdx.x & 63;
    const int c    = lane * 4;

    // ---- per-box setup (wave-uniform) ----
    const float y1 = boxes[box * 4 + 0];
    const float x1 = boxes[box * 4 + 1];
    const float y2 = boxes[box * 4 + 2];
    const float x2 = boxes[box * 4 + 3];
    const float h  = y2 - y1;
    const float w  = x2 - x1;

    // roi_level = clip(ceil(5 + log(h*w)/log(2)), 3, 5) -- match ref op order
    const float lvl  = ceilf(5.0f + logf(h * w) / 0.69314718055994530942f);
    const float lvlc = fminf(fmaxf(lvl, 3.0f), 5.0f);
    const int level  = (int)lvlc;

    const float* feat;
    int H;
    if (level <= 3)      { feat = p3; H = 128; }
    else if (level == 4) { feat = p4; H = 64;  }
    else                 { feat = p5; H = 32;  }
    const int W = H;

    const int b = (box >= N_PER_B) ? 1 : 0;
    feat += (size_t)b * H * W * CCH;

    const float Hm1 = (float)(H - 1);
    const float Wm1 = (float)(W - 1);

    // ys = y1*(H-1) + iy * ((y2-y1)*(H-1)/6)   (match reference exactly)
    const float ys = y1 * Hm1 + (float)iy * (h * Hm1 / 6.0f);
    const bool  vy = (ys >= 0.0f) && (ys <= Hm1);

    const float y0f = floorf(ys);
    const float wy  = ys - y0f;
    const float omwy = 1.0f - wy;

    const int y0i = (int)fminf(fmaxf(y0f,        0.0f), Hm1);
    const int y1i = (int)fminf(fmaxf(y0f + 1.0f, 0.0f), Hm1);

    const float* row0 = feat + (size_t)y0i * W * CCH + c;  // top row, this lane's chans
    const float* row1 = feat + (size_t)y1i * W * CCH + c;  // bottom row

    const float xstep = w * Wm1 / 6.0f;
    float* dst_base = out + ((size_t)box * (PH * PW) + (size_t)iy * PW) * CCH + c;

    // ---- inner loop over pool columns ----
#pragma unroll
    for (int ix = 0; ix < PW; ++ix) {
        const float xs = x1 * Wm1 + (float)ix * xstep;
        const bool  vx = (xs >= 0.0f) && (xs <= Wm1);

        const float x0f = floorf(xs);
        const float wx  = xs - x0f;
        const float omwx = 1.0f - wx;

        const int x0i = (int)fminf(fmaxf(x0f,        0.0f), Wm1);
        const int x1i = (int)fminf(fmaxf(x0f + 1.0f, 0.0f), Wm1);

        const float4 v00 = *(const float4*)(row0 + (size_t)x0i * CCH);
        const float4 v01 = *(const float4*)(row0 + (size_t)x1i * CCH);
        const float4 v10 = *(const float4*)(row1 + (size_t)x0i * CCH);
        const float4 v11 = *(const float4*)(row1 + (size_t)x1i * CCH);

        float4 res;
        res.x = (v00.x * omwx + v01.x * wx) * omwy + (v10.x * omwx + v11.x * wx) * wy;
        res.y = (v00.y * omwx + v01.y * wx) * omwy + (v10.y * omwx + v11.y * wx) * wy;
        res.z = (v00.z * omwx + v01.z * wx) * omwy + (v10.z * omwx + v11.z * wx) * wy;
        res.w = (v00.w * omwx + v01.w * wx) * omwy + (v10.w * omwx + v11.w * wx) * wy;

        if (!(vy && vx)) { res.x = 0.0f; res.y = 0.0f; res.z = 0.0f; res.w = 0.0f; }

        *(float4*)(dst_base + (size_t)ix * CCH) = res;
    }
}

extern "C" void kernel_launch(void* const* d_in, const int* in_sizes, int n_in,
                              void* d_out, int out_size, void* d_ws, size_t ws_size,
                              hipStream_t stream) {
    const float* boxes = (const float*)d_in[0];
    // d_in[1] = positive_indices (unused by reference)
    const float* p3 = (const float*)d_in[2];
    const float* p4 = (const float*)d_in[3];
    const float* p5 = (const float*)d_in[4];
    // d_in[5] = config (unused)
    float* out = (float*)d_out;

    hipLaunchKernelGGL(pyramid_roi_align_kernel, dim3(NBOX), dim3(448), 0, stream,
                       boxes, p3, p4, p5, out);
}